// Round 3
// baseline (14594.203 us; speedup 1.0000x reference)
//
#include <hip/hip_runtime.h>
#include <hip/hip_bf16.h>
#include <stdint.h>

typedef unsigned long long u64;

#define T_LEN 4096
#define E_DIM 1024
#define HHID  512
#define PCOLS 4096
#define NEG_INF   -10000.0f
#define START_TAG 14
#define STOP_TAG  15

__device__ __forceinline__ float sigmoidf_(float x) { return 1.0f / (1.0f + expf(-x)); }

// ------------------------------------------------------------------
// K1: embedding gather + input projection GEMM (fp32, 64x64 tiles)
// P[t][r] = sum_k embed[sent[t]][k] * W[r][k] + (b_ih[r]+b_hh[r])
//   r in [0,2048): w_ih_f ; r in [2048,4096): w_ih_b
// ------------------------------------------------------------------
__global__ __launch_bounds__(256) void gemm_pre(
    const int* __restrict__ sent, const float* __restrict__ embed,
    const float* __restrict__ w_ih_f, const float* __restrict__ w_ih_b,
    const float* __restrict__ b_ih_f, const float* __restrict__ b_hh_f,
    const float* __restrict__ b_ih_b, const float* __restrict__ b_hh_b,
    float* __restrict__ P)
{
    __shared__ float As[16][68];
    __shared__ float Bs[16][68];
    const int tid = threadIdx.x;
    const int t0 = blockIdx.x * 64;
    const int n0 = blockIdx.y * 64;
    const int tx = tid & 15, ty = tid >> 4;
    const int lr = tid >> 2;            // 0..63 row within tile
    const int lk = (tid & 3) << 2;      // 0,4,8,12 k offset
    const float* asrc = embed + (size_t)sent[t0 + lr] * E_DIM;
    const int brow = n0 + lr;
    const float* bsrc = (brow < 2048) ? (w_ih_f + (size_t)brow * E_DIM)
                                      : (w_ih_b + (size_t)(brow - 2048) * E_DIM);
    float acc[4][4] = {};
    for (int k0 = 0; k0 < E_DIM; k0 += 16) {
        float4 av = *(const float4*)(asrc + k0 + lk);
        float4 bv = *(const float4*)(bsrc + k0 + lk);
        __syncthreads();
        As[lk+0][lr]=av.x; As[lk+1][lr]=av.y; As[lk+2][lr]=av.z; As[lk+3][lr]=av.w;
        Bs[lk+0][lr]=bv.x; Bs[lk+1][lr]=bv.y; Bs[lk+2][lr]=bv.z; Bs[lk+3][lr]=bv.w;
        __syncthreads();
        #pragma unroll
        for (int kk = 0; kk < 16; ++kk) {
            float4 a = *(const float4*)&As[kk][ty << 2];
            float4 b = *(const float4*)&Bs[kk][tx << 2];
            acc[0][0]+=a.x*b.x; acc[0][1]+=a.x*b.y; acc[0][2]+=a.x*b.z; acc[0][3]+=a.x*b.w;
            acc[1][0]+=a.y*b.x; acc[1][1]+=a.y*b.y; acc[1][2]+=a.y*b.z; acc[1][3]+=a.y*b.w;
            acc[2][0]+=a.z*b.x; acc[2][1]+=a.z*b.y; acc[2][2]+=a.z*b.z; acc[2][3]+=a.z*b.w;
            acc[3][0]+=a.w*b.x; acc[3][1]+=a.w*b.y; acc[3][2]+=a.w*b.z; acc[3][3]+=a.w*b.w;
        }
    }
    float bias[4];
    #pragma unroll
    for (int j = 0; j < 4; ++j) {
        int n = n0 + (tx << 2) + j;
        bias[j] = (n < 2048) ? (b_ih_f[n] + b_hh_f[n]) : (b_ih_b[n - 2048] + b_hh_b[n - 2048]);
    }
    #pragma unroll
    for (int i = 0; i < 4; ++i) {
        int t = t0 + (ty << 2) + i;
        float4 o = make_float4(acc[i][0] + bias[0], acc[i][1] + bias[1],
                               acc[i][2] + bias[2], acc[i][3] + bias[3]);
        *(float4*)&P[(size_t)t * PCOLS + n0 + (tx << 2)] = o;
    }
}

// ------------------------------------------------------------------
// K2 v2: sequential bidirectional LSTM, wave-owned units.
// 128 blocks: dir = bid&1, slice = bid>>1 (0..63), 8 units/block,
// wave w owns units {u0+2w, u0+2w+1}; all 4 gate-rows per unit are
// computed inside the wave (butterfly shuffle reduce, no cross-wave
// traffic, no LDS reduce, publish straight from the wave).
// W_hh rows live in VGPRs (float4[8] x2, compile-time indexed).
// h exchange: packed u64 {stamp=t+1, f32 bits} agent-scope atomics.
// One __syncthreads per step (hbuf double-buffered).
// ------------------------------------------------------------------
__global__ __launch_bounds__(256) void lstm_seq(
    const float* __restrict__ P,
    const float* __restrict__ w_hh_f, const float* __restrict__ w_hh_b,
    const float* __restrict__ h0, const float* __restrict__ c0,
    u64* __restrict__ hspF, u64* __restrict__ hspB)
{
    __shared__ float hbuf[2][512];
    __shared__ float ps[2][32];          // [parity][unit_local*4 + gate]
    const int tid = threadIdx.x;
    const int dir = blockIdx.x & 1;
    const int slice = blockIdx.x >> 1;   // 0..63
    const int u0 = slice << 3;           // 8 units per block
    const int wv = tid >> 6;             // wave 0..3
    const int l  = tid & 63;
    const int g  = l >> 4;               // gate 0..3 (i,f,g,o)
    const int ch = l & 15;               // col chunk (32 cols each)
    const int uA = u0 + (wv << 1), uB = uA + 1;
    const float* __restrict__ whh = dir ? w_hh_b : w_hh_f;
    u64* hsp = dir ? hspB : hspF;
    const int dirOff = dir << 11;

    // W rows (gate g, unit uA/uB), cols ch*32..+32, pre-rotated by ch so the
    // LDS h-read pattern is bank-staggered (2-way max) while register
    // indices stay compile-time constant.
    float4 wA[8], wB[8];
    {
        const float* rA = whh + (size_t)(g * HHID + uA) * HHID + (ch << 5);
        const float* rB = whh + (size_t)(g * HHID + uB) * HHID + (ch << 5);
        #pragma unroll
        for (int k = 0; k < 8; ++k) {
            const int kk = (k + ch) & 7;
            wA[k] = *(const float4*)(rA + (kk << 2));
            wB[k] = *(const float4*)(rB + (kk << 2));
        }
    }
    float cA = c0[dir * HHID + uA];
    float cB = c0[dir * HHID + uB];
    // prefetch P slice for t=0
    if (tid < 32) {
        const int uu = u0 + (tid >> 2), gg = tid & 3;
        const int tt = dir ? (T_LEN - 1) : 0;
        ps[0][tid] = P[(size_t)tt * PCOLS + dirOff + gg * HHID + uu];
    }
    // stage h0
    hbuf[0][tid]       = h0[dir * HHID + tid];
    hbuf[0][tid + 256] = h0[dir * HHID + tid + 256];
    __syncthreads();

    for (int t = 0; t < T_LEN; ++t) {
        const int par = t & 1;
        // ---- GEMV: rows (g,uA),(g,uB) x h[ch*32..+32], rotated chunks ----
        const float* hrow = &hbuf[par][ch << 5];
        float a0 = 0.0f, a1 = 0.0f;
        #pragma unroll
        for (int k = 0; k < 8; ++k) {
            const int kk = (k + ch) & 7;
            float4 hv = *(const float4*)(hrow + (kk << 2));
            a0 += wA[k].x * hv.x + wA[k].y * hv.y + wA[k].z * hv.z + wA[k].w * hv.w;
            a1 += wB[k].x * hv.x + wB[k].y * hv.y + wB[k].z * hv.z + wB[k].w * hv.w;
        }
        // ---- butterfly over chunk bits: all lanes get full row sums ----
        #pragma unroll
        for (int d = 1; d < 16; d <<= 1) {
            a0 += __shfl_xor(a0, d);
            a1 += __shfl_xor(a1, d);
        }
        // full sums live in every lane of each g-group; gather the 4 gates
        const float siA = __shfl(a0, 0),  sfA = __shfl(a0, 16),
                    sgA = __shfl(a0, 32), soA = __shfl(a0, 48);
        const float siB = __shfl(a1, 0),  sfB = __shfl(a1, 16),
                    sgB = __shfl(a1, 32), soB = __shfl(a1, 48);
        const float* pp = ps[par] + (wv << 3);
        const float iA = sigmoidf_(siA + pp[0]);
        const float fA = sigmoidf_(sfA + pp[1]);
        const float gA = tanhf    (sgA + pp[2]);
        const float oA = sigmoidf_(soA + pp[3]);
        const float iB = sigmoidf_(siB + pp[4]);
        const float fB = sigmoidf_(sfB + pp[5]);
        const float gB = tanhf    (sgB + pp[6]);
        const float oB = sigmoidf_(soB + pp[7]);
        cA = fA * cA + iA * gA;
        cB = fB * cB + iB * gB;
        const float hA = oA * tanhf(cA);
        const float hB = oB * tanhf(cB);
        // ---- publish immediately (lanes 0/1 of each wave) ----
        if (l == 0) {
            u64 pk = ((u64)(unsigned)(t + 1) << 32) | (u64)__float_as_uint(hA);
            __hip_atomic_store(hsp + (size_t)(t + 1) * HHID + uA, pk,
                               __ATOMIC_RELAXED, __HIP_MEMORY_SCOPE_AGENT);
        } else if (l == 1) {
            u64 pk = ((u64)(unsigned)(t + 1) << 32) | (u64)__float_as_uint(hB);
            __hip_atomic_store(hsp + (size_t)(t + 1) * HHID + uB, pk,
                               __ATOMIC_RELAXED, __HIP_MEMORY_SCOPE_AGENT);
        }
        // ---- prefetch next P slice ----
        if (tid < 32 && t + 1 < T_LEN) {
            const int uu = u0 + (tid >> 2), gg = tid & 3;
            const int tt = dir ? (T_LEN - 2 - t) : (t + 1);
            ps[par ^ 1][tid] = P[(size_t)tt * PCOLS + dirOff + gg * HHID + uu];
        }
        // ---- poll + stage h_{t+1} into the other buffer ----
        if (t + 1 < T_LEN) {
            u64* p0 = hsp + (size_t)(t + 1) * HHID + tid;
            u64* p1 = p0 + 256;
            u64 v0 = 0, v1 = 0;
            bool d0 = false, d1 = false;
            do {
                if (!d0) {
                    v0 = __hip_atomic_load(p0, __ATOMIC_RELAXED, __HIP_MEMORY_SCOPE_AGENT);
                    d0 = ((unsigned)(v0 >> 32) == (unsigned)(t + 1));
                }
                if (!d1) {
                    v1 = __hip_atomic_load(p1, __ATOMIC_RELAXED, __HIP_MEMORY_SCOPE_AGENT);
                    d1 = ((unsigned)(v1 >> 32) == (unsigned)(t + 1));
                }
            } while (!(d0 && d1));
            hbuf[par ^ 1][tid]       = __uint_as_float((unsigned)v0);
            hbuf[par ^ 1][tid + 256] = __uint_as_float((unsigned)v1);
        }
        __syncthreads();
    }
}

// ------------------------------------------------------------------
// K3: output projection  feats[t][k] = w_out[k] . [hf[t], hb[t]] + b_out[k]
// hf[t] = hspF[t+1], hb[t] = hspB[T-t]  (low 32 bits of packed words)
// ------------------------------------------------------------------
__global__ __launch_bounds__(256) void feats_kernel(
    const u64* __restrict__ hspF, const u64* __restrict__ hspB,
    const float* __restrict__ w_out, const float* __restrict__ b_out,
    float* __restrict__ feats)
{
    __shared__ float lst[1024];
    const int t = blockIdx.x;
    const int tid = threadIdx.x;
    {
        int e = tid;
        #pragma unroll
        for (int rnd = 0; rnd < 4; ++rnd, e += 256) {
            u64 v;
            if (e < 512)
                v = __hip_atomic_load((u64*)hspF + (size_t)(t + 1) * HHID + e,
                                      __ATOMIC_RELAXED, __HIP_MEMORY_SCOPE_AGENT);
            else
                v = __hip_atomic_load((u64*)hspB + (size_t)(T_LEN - t) * HHID + (e - 512),
                                      __ATOMIC_RELAXED, __HIP_MEMORY_SCOPE_AGENT);
            lst[e] = __uint_as_float((unsigned)v);
        }
    }
    __syncthreads();
    const int k = tid >> 4, s = tid & 15;
    const float* wr = w_out + (size_t)k * 1024 + (s << 6);
    const float* lr = lst + (s << 6);
    float acc = 0.0f;
    #pragma unroll
    for (int c4 = 0; c4 < 16; ++c4) {
        const int cc = ((c4 + s) & 15) << 2;   // stagger: avoid 16-way LDS bank conflict
        float4 w = *(const float4*)(wr + cc);
        float4 x = *(const float4*)(lr + cc);
        acc += w.x * x.x + w.y * x.y + w.z * x.z + w.w * x.w;
    }
    acc += __shfl_xor(acc, 1);
    acc += __shfl_xor(acc, 2);
    acc += __shfl_xor(acc, 4);
    acc += __shfl_xor(acc, 8);
    if (s == 0) feats[t * 16 + k] = acc + b_out[k];
}

// ------------------------------------------------------------------
// K4: Viterbi (K=16) + backtrace. One wave; lane = (tag i)*4 + jchunk.
// Exact numpy argmax tie semantics (first max = smallest index).
// ------------------------------------------------------------------
__global__ __launch_bounds__(64) void viterbi_kernel(
    const float* __restrict__ feats, const float* __restrict__ trans,
    float* __restrict__ out)
{
    __shared__ unsigned char bp[T_LEN][16];   // 64 KiB backpointers
    const int l = threadIdx.x;
    const int i = l >> 2, jc = l & 3;
    float tr[4], pj[4];
    #pragma unroll
    for (int m = 0; m < 4; ++m) {
        tr[m] = trans[i * 16 + jc + 4 * m];
        pj[m] = (jc + 4 * m == START_TAG) ? 0.0f : NEG_INF;
    }
    float fcur = feats[i];
    for (int t = 0; t < T_LEN; ++t) {
        float fnext = (t + 1 < T_LEN) ? feats[(t + 1) * 16 + i] : 0.0f;
        float bv = pj[0] + tr[0];
        int bj = jc;
        #pragma unroll
        for (int m = 1; m < 4; ++m) {
            float v = pj[m] + tr[m];
            if (v > bv) { bv = v; bj = jc + 4 * m; }
        }
        #pragma unroll
        for (int d = 1; d < 4; d <<= 1) {
            float ov = __shfl_xor(bv, d);
            int   oj = __shfl_xor(bj, d);
            if (ov > bv || (ov == bv && oj < bj)) { bv = ov; bj = oj; }
        }
        if (jc == 0) bp[t][i] = (unsigned char)bj;
        float newv = bv + fcur;
        fcur = fnext;
        #pragma unroll
        for (int m = 0; m < 4; ++m) pj[m] = __shfl(newv, (jc + 4 * m) << 2);
    }
    // terminal = prev + trans[STOP]; argmax (min-index ties)
    float bv = pj[0] + trans[STOP_TAG * 16 + jc];
    int bj = jc;
    #pragma unroll
    for (int m = 1; m < 4; ++m) {
        float v = pj[m] + trans[STOP_TAG * 16 + jc + 4 * m];
        if (v > bv) { bv = v; bj = jc + 4 * m; }
    }
    #pragma unroll
    for (int d = 1; d < 4; d <<= 1) {
        float ov = __shfl_xor(bv, d);
        int   oj = __shfl_xor(bj, d);
        if (ov > bv || (ov == bv && oj < bj)) { bv = ov; bj = oj; }
    }
    if (l == 0) {
        out[0] = bv;
        int tag = bj;
        out[1 + T_LEN - 1] = (float)tag;
        for (int t = T_LEN - 1; t >= 1; --t) {
            tag = bp[t][tag];
            out[1 + t - 1] = (float)tag;
        }
    }
}

// ------------------------------------------------------------------
extern "C" void kernel_launch(void* const* d_in, const int* in_sizes, int n_in,
                              void* d_out, int out_size, void* d_ws, size_t ws_size,
                              hipStream_t stream)
{
    const int*   sent   = (const int*)  d_in[0];
    const float* embed  = (const float*)d_in[1];
    const float* w_ih_f = (const float*)d_in[2];
    const float* w_hh_f = (const float*)d_in[3];
    const float* b_ih_f = (const float*)d_in[4];
    const float* b_hh_f = (const float*)d_in[5];
    const float* w_ih_b = (const float*)d_in[6];
    const float* w_hh_b = (const float*)d_in[7];
    const float* b_ih_b = (const float*)d_in[8];
    const float* b_hh_b = (const float*)d_in[9];
    const float* h0     = (const float*)d_in[10];
    const float* c0     = (const float*)d_in[11];
    const float* w_out  = (const float*)d_in[12];
    const float* b_out  = (const float*)d_in[13];
    const float* trans  = (const float*)d_in[14];

    char* ws = (char*)d_ws;
    float* P     = (float*)ws;                                        // 64 MiB
    u64*   hspF  = (u64*)(ws + (size_t)T_LEN * PCOLS * 4);            // 16.8 MiB
    u64*   hspB  = hspF + (size_t)(T_LEN + 1) * HHID;                 // 16.8 MiB
    float* feats = (float*)(hspB + (size_t)(T_LEN + 1) * HHID);       // 256 KiB
    float* outf  = (float*)d_out;

    gemm_pre<<<dim3(64, 64), 256, 0, stream>>>(sent, embed, w_ih_f, w_ih_b,
                                               b_ih_f, b_hh_f, b_ih_b, b_hh_b, P);
    lstm_seq<<<128, 256, 0, stream>>>(P, w_hh_f, w_hh_b, h0, c0, hspF, hspB);
    feats_kernel<<<T_LEN, 256, 0, stream>>>(hspF, hspB, w_out, b_out, feats);
    viterbi_kernel<<<1, 64, 0, stream>>>(feats, trans, outf);
}

// Round 5
// 5840.206 us; speedup vs baseline: 2.4989x; 2.4989x over previous
//
#include <hip/hip_runtime.h>
#include <hip/hip_bf16.h>
#include <stdint.h>

typedef unsigned long long u64;

#define T_LEN 4096
#define E_DIM 1024
#define HHID  512
#define PCOLS 4096
#define SEGLEN 1024
#define WARMUP 96
#define NEG_INF   -10000.0f
#define START_TAG 14
#define STOP_TAG  15

__device__ __forceinline__ float sigmoidf_(float x) { return 1.0f / (1.0f + expf(-x)); }

// ------------------------------------------------------------------
// K1: embedding gather + input projection GEMM (fp32, 64x64 tiles)
// ------------------------------------------------------------------
__global__ __launch_bounds__(256) void gemm_pre(
    const int* __restrict__ sent, const float* __restrict__ embed,
    const float* __restrict__ w_ih_f, const float* __restrict__ w_ih_b,
    const float* __restrict__ b_ih_f, const float* __restrict__ b_hh_f,
    const float* __restrict__ b_ih_b, const float* __restrict__ b_hh_b,
    float* __restrict__ P)
{
    __shared__ float As[16][68];
    __shared__ float Bs[16][68];
    const int tid = threadIdx.x;
    const int t0 = blockIdx.x * 64;
    const int n0 = blockIdx.y * 64;
    const int tx = tid & 15, ty = tid >> 4;
    const int lr = tid >> 2;
    const int lk = (tid & 3) << 2;
    const float* asrc = embed + (size_t)sent[t0 + lr] * E_DIM;
    const int brow = n0 + lr;
    const float* bsrc = (brow < 2048) ? (w_ih_f + (size_t)brow * E_DIM)
                                      : (w_ih_b + (size_t)(brow - 2048) * E_DIM);
    float acc[4][4] = {};
    for (int k0 = 0; k0 < E_DIM; k0 += 16) {
        float4 av = *(const float4*)(asrc + k0 + lk);
        float4 bv = *(const float4*)(bsrc + k0 + lk);
        __syncthreads();
        As[lk+0][lr]=av.x; As[lk+1][lr]=av.y; As[lk+2][lr]=av.z; As[lk+3][lr]=av.w;
        Bs[lk+0][lr]=bv.x; Bs[lk+1][lr]=bv.y; Bs[lk+2][lr]=bv.z; Bs[lk+3][lr]=bv.w;
        __syncthreads();
        #pragma unroll
        for (int kk = 0; kk < 16; ++kk) {
            float4 a = *(const float4*)&As[kk][ty << 2];
            float4 b = *(const float4*)&Bs[kk][tx << 2];
            acc[0][0]+=a.x*b.x; acc[0][1]+=a.x*b.y; acc[0][2]+=a.x*b.z; acc[0][3]+=a.x*b.w;
            acc[1][0]+=a.y*b.x; acc[1][1]+=a.y*b.y; acc[1][2]+=a.y*b.z; acc[1][3]+=a.y*b.w;
            acc[2][0]+=a.z*b.x; acc[2][1]+=a.z*b.y; acc[2][2]+=a.z*b.z; acc[2][3]+=a.z*b.w;
            acc[3][0]+=a.w*b.x; acc[3][1]+=a.w*b.y; acc[3][2]+=a.w*b.z; acc[3][3]+=a.w*b.w;
        }
    }
    float bias[4];
    #pragma unroll
    for (int j = 0; j < 4; ++j) {
        int n = n0 + (tx << 2) + j;
        bias[j] = (n < 2048) ? (b_ih_f[n] + b_hh_f[n]) : (b_ih_b[n - 2048] + b_hh_b[n - 2048]);
    }
    #pragma unroll
    for (int i = 0; i < 4; ++i) {
        int t = t0 + (ty << 2) + i;
        float4 o = make_float4(acc[i][0] + bias[0], acc[i][1] + bias[1],
                               acc[i][2] + bias[2], acc[i][3] + bias[3]);
        *(float4*)&P[(size_t)t * PCOLS + n0 + (tx << 2)] = o;
    }
}

// ------------------------------------------------------------------
// K2 v3: segment-parallel bidirectional LSTM.
// 8 groups x 32 blocks. group = bid&7 (XCD-co-located if round-robin),
// blk = bid>>3. dir = grp>>2, seg = grp&3. Each group runs its segment's
// 1024 steps (+96 warm-up from zeros for seg>0; contraction makes the
// state exact to fp32 by the segment start). Warm-up h-exchange goes to a
// private per-group region; main-range publishes go to the shared hsp
// arrays at globally disjoint indices (seg*1024+1 .. (seg+1)*1024).
// Per block: 16 units; per wave: 4 units, weights in VGPRs (float4 w[4][8]).
// Stamped u64 {stamp, f32} relaxed agent atomics; 2-gen pipelined poll.
// ------------------------------------------------------------------
__global__ __launch_bounds__(256) void lstm_seq(
    const float* __restrict__ P,
    const float* __restrict__ w_hh_f, const float* __restrict__ w_hh_b,
    const float* __restrict__ h0, const float* __restrict__ c0,
    u64* __restrict__ hspF, u64* __restrict__ hspB, u64* __restrict__ warm)
{
    __shared__ float hbuf[2][512];
    __shared__ float ps[2][64];          // [unit_local*4 + gate]
    const int tid = threadIdx.x;
    const int grp = blockIdx.x & 7;
    const int blk = blockIdx.x >> 3;     // 0..31
    const int dir = grp >> 2;
    const int seg = grp & 3;
    const int wv = tid >> 6;             // wave 0..3
    const int l  = tid & 63;
    const int g  = l >> 4;               // gate 0..3 (i,f,g,o)
    const int ch = l & 15;               // col chunk (32 cols)
    const int u0 = (blk << 4) + (wv << 2);   // first of this wave's 4 units
    const float* __restrict__ whh = dir ? w_hh_b : w_hh_f;
    u64* hsp = dir ? hspB : hspF;
    u64* wrm = warm + (size_t)grp * (128 * 512);
    const int dirOff = dir << 11;
    const int segBase = seg * SEGLEN;
    const int sStart = seg ? (segBase - WARMUP) : 0;
    const int sEnd = segBase + SEGLEN;

    // ---- weights: 4 units x 4 gates-row-slice, rotated by ch ----
    float4 w[4][8];
    #pragma unroll
    for (int m = 0; m < 4; ++m) {
        const float* r = whh + (size_t)(g * HHID + u0 + m) * HHID + (ch << 5);
        #pragma unroll
        for (int k = 0; k < 8; ++k)
            w[m][k] = *(const float4*)(r + (((k + ch) & 7) << 2));
    }
    float c[4];
    #pragma unroll
    for (int m = 0; m < 4; ++m)
        c[m] = seg ? 0.0f : c0[dir * HHID + u0 + m];

    // ---- ps prefetch for first step ----
    if (tid < 64) {
        const int ul = tid >> 2, gg = tid & 3;
        const int tt = dir ? (T_LEN - 1 - sStart) : sStart;
        ps[0][tid] = P[(size_t)tt * PCOLS + dirOff + gg * HHID + (blk << 4) + ul];
    }
    // ---- initial h ----
    if (seg == 0) {
        hbuf[0][tid]       = h0[dir * HHID + tid];
        hbuf[0][tid + 256] = h0[dir * HHID + tid + 256];
    } else {
        hbuf[0][tid] = 0.0f;
        hbuf[0][tid + 256] = 0.0f;
    }
    __syncthreads();

    for (int s = sStart; s < sEnd; ++s) {
        const int par = (s - sStart) & 1;
        // ---- GEMV: 4 rows (gate g, units u0..u0+3) x h chunk ----
        const float* hrow = &hbuf[par][ch << 5];
        float a0 = 0.f, a1 = 0.f, a2 = 0.f, a3 = 0.f;
        #pragma unroll
        for (int k = 0; k < 8; ++k) {
            const int kk = (k + ch) & 7;
            float4 hv = *(const float4*)(hrow + (kk << 2));
            a0 += w[0][k].x*hv.x + w[0][k].y*hv.y + w[0][k].z*hv.z + w[0][k].w*hv.w;
            a1 += w[1][k].x*hv.x + w[1][k].y*hv.y + w[1][k].z*hv.z + w[1][k].w*hv.w;
            a2 += w[2][k].x*hv.x + w[2][k].y*hv.y + w[2][k].z*hv.z + w[2][k].w*hv.w;
            a3 += w[3][k].x*hv.x + w[3][k].y*hv.y + w[3][k].z*hv.z + w[3][k].w*hv.w;
        }
        #pragma unroll
        for (int d = 1; d < 16; d <<= 1) {
            a0 += __shfl_xor(a0, d);
            a1 += __shfl_xor(a1, d);
            a2 += __shfl_xor(a2, d);
            a3 += __shfl_xor(a3, d);
        }
        // full row sums: lane g*16 of each gate group holds gate g's sum
        float si[4], sf[4], sg[4], so[4];
        si[0]=__shfl(a0,0);  sf[0]=__shfl(a0,16); sg[0]=__shfl(a0,32); so[0]=__shfl(a0,48);
        si[1]=__shfl(a1,0);  sf[1]=__shfl(a1,16); sg[1]=__shfl(a1,32); so[1]=__shfl(a1,48);
        si[2]=__shfl(a2,0);  sf[2]=__shfl(a2,16); sg[2]=__shfl(a2,32); so[2]=__shfl(a2,48);
        si[3]=__shfl(a3,0);  sf[3]=__shfl(a3,16); sg[3]=__shfl(a3,32); so[3]=__shfl(a3,48);
        const float* pp = &ps[par][wv << 4];
        float hnew[4];
        #pragma unroll
        for (int m = 0; m < 4; ++m) {
            const float ig = sigmoidf_(si[m] + pp[(m << 2) + 0]);
            const float fg = sigmoidf_(sf[m] + pp[(m << 2) + 1]);
            const float gv = tanhf    (sg[m] + pp[(m << 2) + 2]);
            const float og = sigmoidf_(so[m] + pp[(m << 2) + 3]);
            c[m] = fg * c[m] + ig * gv;
            hnew[m] = og * tanhf(c[m]);
        }
        const int sp = s + 1;
        const bool priv = (sp <= segBase);     // seg==0 -> never
        const unsigned stamp = priv ? (unsigned)(sp - sStart) : (unsigned)sp;
        u64* base = priv ? (wrm + (size_t)(sp - sStart) * HHID)
                         : (hsp + (size_t)sp * HHID);
        // ---- publish: lanes 0..3 publish this wave's 4 units ----
        if (l < 4) {
            const float hv = (l == 0) ? hnew[0] : (l == 1) ? hnew[1]
                           : (l == 2) ? hnew[2] : hnew[3];
            u64 pk = ((u64)stamp << 32) | (u64)__float_as_uint(hv);
            __hip_atomic_store(base + u0 + l, pk,
                               __ATOMIC_RELAXED, __HIP_MEMORY_SCOPE_AGENT);
        }
        // ---- prefetch ps for s+1 ----
        if (tid < 64 && sp < sEnd) {
            const int ul = tid >> 2, gg = tid & 3;
            const int tt = dir ? (T_LEN - 1 - sp) : sp;
            ps[par ^ 1][tid] = P[(size_t)tt * PCOLS + dirOff + gg * HHID + (blk << 4) + ul];
        }
        // ---- poll + stage h_{s+1} (2-generation pipelined) ----
        if (sp < sEnd) {
            u64* p0 = base + tid;
            u64* p1 = p0 + 256;
            u64 v0 = 0, v1 = 0;
            bool d0 = false, d1 = false;
            do {
                u64 x0 = 0, x1 = 0, y0 = 0, y1 = 0;
                if (!d0) {
                    x0 = __hip_atomic_load(p0, __ATOMIC_RELAXED, __HIP_MEMORY_SCOPE_AGENT);
                    y0 = __hip_atomic_load(p0, __ATOMIC_RELAXED, __HIP_MEMORY_SCOPE_AGENT);
                }
                if (!d1) {
                    x1 = __hip_atomic_load(p1, __ATOMIC_RELAXED, __HIP_MEMORY_SCOPE_AGENT);
                    y1 = __hip_atomic_load(p1, __ATOMIC_RELAXED, __HIP_MEMORY_SCOPE_AGENT);
                }
                if (!d0) {
                    if ((unsigned)(x0 >> 32) == stamp) { v0 = x0; d0 = true; }
                    else if ((unsigned)(y0 >> 32) == stamp) { v0 = y0; d0 = true; }
                }
                if (!d1) {
                    if ((unsigned)(x1 >> 32) == stamp) { v1 = x1; d1 = true; }
                    else if ((unsigned)(y1 >> 32) == stamp) { v1 = y1; d1 = true; }
                }
            } while (!(d0 && d1));
            hbuf[par ^ 1][tid]       = __uint_as_float((unsigned)v0);
            hbuf[par ^ 1][tid + 256] = __uint_as_float((unsigned)v1);
        }
        __syncthreads();
    }
}

// ------------------------------------------------------------------
// K3: output projection  feats[t][k] = w_out[k] . [hf[t], hb[t]] + b_out[k]
// ------------------------------------------------------------------
__global__ __launch_bounds__(256) void feats_kernel(
    const u64* __restrict__ hspF, const u64* __restrict__ hspB,
    const float* __restrict__ w_out, const float* __restrict__ b_out,
    float* __restrict__ feats)
{
    __shared__ float lst[1024];
    const int t = blockIdx.x;
    const int tid = threadIdx.x;
    {
        int e = tid;
        #pragma unroll
        for (int rnd = 0; rnd < 4; ++rnd, e += 256) {
            u64 v;
            if (e < 512)
                v = __hip_atomic_load((u64*)hspF + (size_t)(t + 1) * HHID + e,
                                      __ATOMIC_RELAXED, __HIP_MEMORY_SCOPE_AGENT);
            else
                v = __hip_atomic_load((u64*)hspB + (size_t)(T_LEN - t) * HHID + (e - 512),
                                      __ATOMIC_RELAXED, __HIP_MEMORY_SCOPE_AGENT);
            lst[e] = __uint_as_float((unsigned)v);
        }
    }
    __syncthreads();
    const int k = tid >> 4, s = tid & 15;
    const float* wr = w_out + (size_t)k * 1024 + (s << 6);
    const float* lr = lst + (s << 6);
    float acc = 0.0f;
    #pragma unroll
    for (int c4 = 0; c4 < 16; ++c4) {
        const int cc = ((c4 + s) & 15) << 2;
        float4 w = *(const float4*)(wr + cc);
        float4 x = *(const float4*)(lr + cc);
        acc += w.x * x.x + w.y * x.y + w.z * x.z + w.w * x.w;
    }
    acc += __shfl_xor(acc, 1);
    acc += __shfl_xor(acc, 2);
    acc += __shfl_xor(acc, 4);
    acc += __shfl_xor(acc, 8);
    if (s == 0) feats[t * 16 + k] = acc + b_out[k];
}

// ------------------------------------------------------------------
// K4: Viterbi (K=16) + backtrace, exact numpy argmax tie semantics.
// ------------------------------------------------------------------
__global__ __launch_bounds__(64) void viterbi_kernel(
    const float* __restrict__ feats, const float* __restrict__ trans,
    float* __restrict__ out)
{
    __shared__ unsigned char bp[T_LEN][16];
    const int l = threadIdx.x;
    const int i = l >> 2, jc = l & 3;
    float tr[4], pj[4];
    #pragma unroll
    for (int m = 0; m < 4; ++m) {
        tr[m] = trans[i * 16 + jc + 4 * m];
        pj[m] = (jc + 4 * m == START_TAG) ? 0.0f : NEG_INF;
    }
    float fcur = feats[i];
    for (int t = 0; t < T_LEN; ++t) {
        float fnext = (t + 1 < T_LEN) ? feats[(t + 1) * 16 + i] : 0.0f;
        float bv = pj[0] + tr[0];
        int bj = jc;
        #pragma unroll
        for (int m = 1; m < 4; ++m) {
            float v = pj[m] + tr[m];
            if (v > bv) { bv = v; bj = jc + 4 * m; }
        }
        #pragma unroll
        for (int d = 1; d < 4; d <<= 1) {
            float ov = __shfl_xor(bv, d);
            int   oj = __shfl_xor(bj, d);
            if (ov > bv || (ov == bv && oj < bj)) { bv = ov; bj = oj; }
        }
        if (jc == 0) bp[t][i] = (unsigned char)bj;
        float newv = bv + fcur;
        fcur = fnext;
        #pragma unroll
        for (int m = 0; m < 4; ++m) pj[m] = __shfl(newv, (jc + 4 * m) << 2);
    }
    float bv = pj[0] + trans[STOP_TAG * 16 + jc];
    int bj = jc;
    #pragma unroll
    for (int m = 1; m < 4; ++m) {
        float v = pj[m] + trans[STOP_TAG * 16 + jc + 4 * m];
        if (v > bv) { bv = v; bj = jc + 4 * m; }
    }
    #pragma unroll
    for (int d = 1; d < 4; d <<= 1) {
        float ov = __shfl_xor(bv, d);
        int   oj = __shfl_xor(bj, d);
        if (ov > bv || (ov == bv && oj < bj)) { bv = ov; bj = oj; }
    }
    if (l == 0) {
        out[0] = bv;
        int tag = bj;
        out[1 + T_LEN - 1] = (float)tag;
        for (int t = T_LEN - 1; t >= 1; --t) {
            tag = bp[t][tag];
            out[1 + t - 1] = (float)tag;
        }
    }
}

// ------------------------------------------------------------------
extern "C" void kernel_launch(void* const* d_in, const int* in_sizes, int n_in,
                              void* d_out, int out_size, void* d_ws, size_t ws_size,
                              hipStream_t stream)
{
    const int*   sent   = (const int*)  d_in[0];
    const float* embed  = (const float*)d_in[1];
    const float* w_ih_f = (const float*)d_in[2];
    const float* w_hh_f = (const float*)d_in[3];
    const float* b_ih_f = (const float*)d_in[4];
    const float* b_hh_f = (const float*)d_in[5];
    const float* w_ih_b = (const float*)d_in[6];
    const float* w_hh_b = (const float*)d_in[7];
    const float* b_ih_b = (const float*)d_in[8];
    const float* b_hh_b = (const float*)d_in[9];
    const float* h0     = (const float*)d_in[10];
    const float* c0     = (const float*)d_in[11];
    const float* w_out  = (const float*)d_in[12];
    const float* b_out  = (const float*)d_in[13];
    const float* trans  = (const float*)d_in[14];

    char* ws = (char*)d_ws;
    float* P     = (float*)ws;                                        // 64 MiB
    u64*   hspF  = (u64*)(ws + (size_t)T_LEN * PCOLS * 4);            // 16.8 MiB
    u64*   hspB  = hspF + (size_t)(T_LEN + 1) * HHID;                 // 16.8 MiB
    float* feats = (float*)(hspB + (size_t)(T_LEN + 1) * HHID);       // 256 KiB
    u64*   warm  = (u64*)(feats + (size_t)T_LEN * 16);                // 4 MiB
    float* outf  = (float*)d_out;

    gemm_pre<<<dim3(64, 64), 256, 0, stream>>>(sent, embed, w_ih_f, w_ih_b,
                                               b_ih_f, b_hh_f, b_ih_b, b_hh_b, P);
    lstm_seq<<<256, 256, 0, stream>>>(P, w_hh_f, w_hh_b, h0, c0, hspF, hspB, warm);
    feats_kernel<<<T_LEN, 256, 0, stream>>>(hspF, hspB, w_out, b_out, feats);
    viterbi_kernel<<<1, 64, 0, stream>>>(feats, trans, outf);
}